// Round 4
// baseline (121.554 us; speedup 1.0000x reference)
//
#include <hip/hip_runtime.h>

#define NQ  12
#define DIM 4096
#define TPB 128

typedef float v2f __attribute__((ext_vector_type(2)));
typedef float v4f __attribute__((ext_vector_type(4)));

// ---------------------------------------------------------------------------
// 3-pass structure: 128 threads x 32 amps/thread (5 register bits) -> 4 gate
// layers per pass -> only TWO LDS exchanges (vs 3 in the 4-pass version).
// LDS = 32768 B exactly -> 5 blocks/CU. Swizzle slot(e) = e ^ (((e>>5)&7)<<1)
// (round-2, measured ~0 conflicts). Per-16-lane-phase bank check:
//   Ex1 write b128, e=32t+2k:        quad = k^(t&7)               -> min
//   Ex1 read/Ex2 write b64,
//     e=(t&15)+16r+512(t>>4):        pair = (t&15)^(((r>>1)&7)<<1) -> min
//   Ex2 read b128, e=2t+256*rh:      quad = (t&7)^(t>>4)           -> min
//     (xor term depends only on t -> folds into base, per-rh = ds offset imm)
// Register-bit windows: P1 regs = e bits 0-4 (qubits 0-3), P2 regs = e bits
// 4-8 (qubits 4-7), P3 regs bits0-3 = e bits 8-11, bit4 = e bit 0 (qubits
// 8-11; layer 11 ctrl=bit11->MC=8, tgt=bit0->MT=16, no CNOT).
// Round-3 lesson: dense-load + x-staging regressed (strided loads were
// already hidden); loads here are direct 128B/lane-stride float4.
// ---------------------------------------------------------------------------

__device__ __forceinline__ float wave_reduce(float v) {
#pragma unroll
    for (int m = 32; m >= 1; m >>= 1) v += __shfl_xor(v, m, 64);
    return v;
}

// broadcast lane q's value to all lanes (lands in SGPR)
#define BCAST(v, q) __uint_as_float(__builtin_amdgcn_readlane(__float_as_uint(v), (q)))

// One circuit layer on 32 regs: unnormalized H on register-bit MC (1/sqrt2
// folded into epilogue), then (X*RX if XGATE else RX) on bit MT where MC==1.
// ctv = (c,c), snv = (s,-s); off-diag = -i*s, so (-i*s)*z = snv * z.yx.
template <int MC, int MT, bool XGATE>
__device__ __forceinline__ void apply_layer(v2f* a, v2f ctv, v2f snv) {
#pragma unroll
    for (int i = 0; i < 32; ++i) {
        if (i & MC) continue;
        const int j = i | MC;
        const v2f t0 = a[i], t1 = a[j];
        a[i] = t0 + t1;          // v_pk_add_f32
        a[j] = t0 - t1;
    }
#pragma unroll
    for (int i = 0; i < 32; ++i) {
        if (!(i & MC) || (i & MT)) continue;   // control=1, target=0 slot
        const int j = i | MT;
        const v2f b0 = a[i], b1 = a[j];
        const v2f s0 = snv * b0.yx;            // v_pk_mul_f32
        const v2f s1 = snv * b1.yx;
        if (XGATE) {                           // X*RX = [[s, c],[c, s]]
            a[i] = ctv * b1 + s0;              // v_pk_fma_f32
            a[j] = ctv * b0 + s1;
        } else {                               // RX = [[c, s],[s, c]]
            a[i] = ctv * b0 + s1;
            a[j] = ctv * b1 + s0;
        }
    }
}

__global__ __launch_bounds__(TPB, 2) void qlayer_kernel(
        const float* __restrict__ state, const float* __restrict__ params,
        float* __restrict__ out) {
    __shared__ __align__(16) v2f amp[DIM];     // 32768 B exactly -> 5 blocks/CU
    char* const lds = (char*)amp;

    const int t = threadIdx.x;
    const int lane = t & 63;
    const long long sbase = (long long)blockIdx.x * DIM;

    // per-lane angle (lanes 0..11 hold cos/sin(theta_q/2)); broadcast via readlane
    const float th = params[lane < NQ ? lane : 0] * 0.5f;
    const float cl = cosf(th);
    const float sl = sinf(th);

    // ---- load 32 contiguous floats (128 B/thread) + norm reduction ----
    const float4* gp = (const float4*)(state + sbase + t * 32);
    float4 xv[8];
    float ss = 0.f;
#pragma unroll
    for (int j = 0; j < 8; ++j) {
        const float4 v = gp[j];
        xv[j] = v;
        ss = fmaf(v.x, v.x, ss); ss = fmaf(v.y, v.y, ss);
        ss = fmaf(v.z, v.z, ss); ss = fmaf(v.w, v.w, ss);
    }
    ss = wave_reduce(ss);
    if (lane == 0) ((float*)lds)[t >> 6] = ss;   // 2 waves -> partials [0],[1]
    __syncthreads();                             // bar1: partials visible
    const float nrm  = sqrtf(((const float*)lds)[0] + ((const float*)lds)[1]);
    const float invd = 1.0f / (nrm + 1e-8f);
    __syncthreads();                             // bar2: partials consumed

    // ---- encoding: re = clamp(v,-1,1); im = sign(v)*sqrt(1-re^2) ----
    // |q|^2 == 1 exactly => second normalization = 1/4096, folded into epilogue.
    v2f a[32];
#define ENC(k, xval)                                                      \
    {                                                                     \
        const float v   = (xval) * invd;                                  \
        const float re  = fminf(fmaxf(v, -1.0f), 1.0f);                   \
        const float imb = __builtin_amdgcn_sqrtf(fmaxf(1.0f - re * re, 0.f)); \
        const float im  = (v > 0.f) ? imb : ((v < 0.f) ? -imb : 0.f);     \
        v2f q; q.x = re; q.y = im;                                        \
        a[k] = q;                                                         \
    }
#pragma unroll
    for (int j = 0; j < 8; ++j) {
        const float4 xq = xv[j];
        ENC(4 * j + 0, xq.x); ENC(4 * j + 1, xq.y);
        ENC(4 * j + 2, xq.z); ENC(4 * j + 3, xq.w);
    }
#undef ENC

#define CTV(q) ({ v2f _c; _c.x = BCAST(cl, q); _c.y = _c.x; _c; })
#define SNV(q) ({ float _s = BCAST(sl, q); v2f _v; _v.x = _s; _v.y = -_s; _v; })

    // ---- pass 1: qubits 0-3 on regs = e bits 0-4 (e = 32t + r) ----
    apply_layer<1,  2, true>(a, CTV(0), SNV(0));
    apply_layer<2,  4, true>(a, CTV(1), SNV(1));
    apply_layer<4,  8, true>(a, CTV(2), SNV(2));
    apply_layer<8, 16, true>(a, CTV(3), SNV(3));

    // ex1 write b128: byte = 256t + (16k ^ ((t&7)<<4))
    {
        const int base1 = (t << 8) | ((t & 7) << 4);
#pragma unroll
        for (int k = 0; k < 16; ++k) {
            v4f w; w.x = a[2 * k].x;     w.y = a[2 * k].y;
            w.z = a[2 * k + 1].x; w.w = a[2 * k + 1].y;
            *(v4f*)(lds + (base1 ^ (k << 4))) = w;
        }
    }
    __syncthreads();                             // bar3

    // ---- pass 2: qubits 4-7 on regs = e bits 4-8 ----
    // e = (t&15) + 16r + 512(t>>4); byte = (B2 ^ (((r>>1)&7)<<4)) + 128r
    const int B2 = ((t & 15) << 3) + ((t >> 4) << 12);
#pragma unroll
    for (int r = 0; r < 32; ++r)
        a[r] = *(const v2f*)(lds + ((B2 ^ (((r >> 1) & 7) << 4)) + (r << 7)));

    apply_layer<1,  2, true>(a, CTV(4), SNV(4));
    apply_layer<2,  4, true>(a, CTV(5), SNV(5));
    apply_layer<4,  8, true>(a, CTV(6), SNV(6));
    apply_layer<8, 16, true>(a, CTV(7), SNV(7));

#pragma unroll
    for (int r = 0; r < 32; ++r)
        *(v2f*)(lds + ((B2 ^ (((r >> 1) & 7) << 4)) + (r << 7))) = a[r];
    __syncthreads();                             // bar4

    // ---- pass 3: qubits 8-11 on regs bits0-3 = e bits 8-11, bit4 = e bit 0 ----
    // e_even = 2t + 256*rh; byte = F + 2048*rh (pure ds offset immediates)
    {
        const int F = (t << 4) ^ (((t >> 4) & 7) << 4);
#pragma unroll
        for (int rh = 0; rh < 16; ++rh) {
            const v4f v = *(const v4f*)(lds + (F + (rh << 11)));
            v2f q0; q0.x = v.x; q0.y = v.y;      // e bit0 = 0
            v2f q1; q1.x = v.z; q1.y = v.w;      // e bit0 = 1
            a[rh]      = q0;
            a[rh + 16] = q1;
        }
        apply_layer<1,  2, true >(a, CTV(8),  SNV(8));
        apply_layer<2,  4, true >(a, CTV(9),  SNV(9));
        apply_layer<4,  8, true >(a, CTV(10), SNV(10));
        apply_layer<8, 16, false>(a, CTV(11), SNV(11));   // ctrl=b11, tgt=b0

        // probs epilogue; scale = 1/4096 (encode norm) * (1/sqrt2)^24 = 2^-24
        // thread writes float2 {e, e+1} at e = 2t + 256*rh -> 512B/wave dense;
        // non-temporal: 64 MB write stream, never re-read.
        v2f sc2; sc2.x = 0x1p-24f; sc2.y = 0x1p-24f;
        v2f* outp = (v2f*)(out + sbase);
#pragma unroll
        for (int rh = 0; rh < 16; ++rh) {
            const v2f q0 = a[rh] * a[rh];             // v_pk_mul_f32
            const v2f q1 = a[rh + 16] * a[rh + 16];
            v2f res; res.x = q0.x + q0.y;
            res.y = q1.x + q1.y;
            res = res * sc2;                          // v_pk_mul_f32
            __builtin_nontemporal_store(res, outp + t + (rh << 7));
        }
    }
#undef CTV
#undef SNV
}

extern "C" void kernel_launch(void* const* d_in, const int* in_sizes, int n_in,
                              void* d_out, int out_size, void* d_ws, size_t ws_size,
                              hipStream_t stream) {
    (void)in_sizes; (void)n_in; (void)out_size; (void)d_ws; (void)ws_size;
    const float* state  = (const float*)d_in[0];   // (8,512,4096) fp32
    const float* params = (const float*)d_in[1];   // (12,) fp32
    float* out = (float*)d_out;                    // (8,512,4096) fp32
    qlayer_kernel<<<dim3(4096), dim3(TPB), 0, stream>>>(state, params, out);
}

// Round 5
// 115.565 us; speedup vs baseline: 1.0518x; 1.0518x over previous
//
#include <hip/hip_runtime.h>

#define NQ  12
#define DIM 4096
#define TPB 256

typedef float v2f __attribute__((ext_vector_type(2)));
typedef float v4f __attribute__((ext_vector_type(4)));

// ---------------------------------------------------------------------------
// Round-2 shape (256 thr x 16 amps, 4 passes, 5 barriers, 32768 B LDS = 5
// blocks/CU = 20 waves/CU) but ALL exchange traffic is b128 (48 ops/thread vs
// 16 b128 + 64 b64 before). Each inter-pass interval gets its own layout Lx
// whose slot bit0 = the e-bit the READING pass pairs on:
//   L1 (P1w/P2r): raw = (e3<<3)|((e&7)<<4)|((e>>4)<<7)
//   L2 (P2w/P3r): raw = (e6<<3)|((e&63)<<4)|((e>>7)<<10)
//   L3 (P3w/P4r): raw = (e9<<3)|((e&511)<<4)|((e>>10)<<13)
// swizzle (all): addr = raw ^ (((raw>>7 ^ raw>>10)&7)<<4)
// In-place safety: P2's write set == its read set == {base2 ^ (i<<7|i<<4)},
// P3's == {base3 ^ (i<<10|i<<4)} (renaming i) -> per-thread RMW, no extra
// barriers. Bank check per 16-lane phase (quad = addr bits 4-6):
//   P1w: p^(t&7)^((t>>3)&7)          -> 2 lanes/quad (min)
//   P2r/P2w: (t&7)^((t>>3)&7)^m      -> min     P3r/P3w: same form -> min
//   P4r: (2(t&3)+b0)^((t>>2)&7)^((t>>5)&7), (t>>5) const/phase -> min
// Round-3/4 lessons kept: direct strided loads (no x-staging); 256-thread
// blocks (20 waves/CU) beat 128-thread (10 waves) -- latency-sensitive.
// ---------------------------------------------------------------------------

__device__ __forceinline__ float wave_reduce(float v) {
#pragma unroll
    for (int m = 32; m >= 1; m >>= 1) v += __shfl_xor(v, m, 64);
    return v;
}

// broadcast lane q's value to all lanes (lands in SGPR)
#define BCAST(v, q) __uint_as_float(__builtin_amdgcn_readlane(__float_as_uint(v), (q)))

// One circuit layer: unnormalized H on register-bit MC (1/sqrt2 folded into
// epilogue), then (X*RX if XGATE else RX) on bit MT where MC==1.
// ctv = (c,c), snv = (s,-s); off-diag = -i*s, so (-i*s)*z = snv * z.yx.
template <int MC, int MT, bool XGATE>
__device__ __forceinline__ void apply_layer(v2f* a, v2f ctv, v2f snv) {
#pragma unroll
    for (int i = 0; i < 16; ++i) {
        if (i & MC) continue;
        const int j = i | MC;
        const v2f t0 = a[i], t1 = a[j];
        a[i] = t0 + t1;          // v_pk_add_f32
        a[j] = t0 - t1;
    }
#pragma unroll
    for (int i = 0; i < 16; ++i) {
        if (!(i & MC) || (i & MT)) continue;   // control=1, target=0 slot
        const int j = i | MT;
        const v2f b0 = a[i], b1 = a[j];
        const v2f s0 = snv * b0.yx;            // v_pk_mul_f32
        const v2f s1 = snv * b1.yx;
        if (XGATE) {                           // X*RX = [[s, c],[c, s]]
            a[i] = ctv * b1 + s0;              // v_pk_fma_f32
            a[j] = ctv * b0 + s1;
        } else {                               // RX = [[c, s],[s, c]]
            a[i] = ctv * b0 + s1;
            a[j] = ctv * b1 + s0;
        }
    }
}

__global__ __launch_bounds__(TPB, 5) void qlayer_kernel(
        const float* __restrict__ state, const float* __restrict__ params,
        float* __restrict__ out) {
    __shared__ __align__(16) v2f amp[DIM];     // 32768 B exactly -> 5 blocks/CU
    char* const lds = (char*)amp;

    const int t = threadIdx.x;
    const int lane = t & 63;
    const long long sbase = (long long)blockIdx.x * DIM;

    // per-lane angle (lanes 0..11 hold cos/sin(theta_q/2)); broadcast via readlane
    const float th = params[lane < NQ ? lane : 0] * 0.5f;
    const float cl = cosf(th);
    const float sl = sinf(th);

    // ---- load 16 contiguous floats (64 B/thread) + norm reduction ----
    const float4* gp = (const float4*)(state + sbase + t * 16);
    float4 xv[4];
    float ss = 0.f;
#pragma unroll
    for (int j = 0; j < 4; ++j) {
        const float4 v = gp[j];
        xv[j] = v;
        ss = fmaf(v.x, v.x, ss); ss = fmaf(v.y, v.y, ss);
        ss = fmaf(v.z, v.z, ss); ss = fmaf(v.w, v.w, ss);
    }
    ss = wave_reduce(ss);
    if (lane == 0) ((float*)lds)[t >> 6] = ss;
    __syncthreads();                           // bar1: partials visible
    const float* redp = (const float*)lds;
    const float nrm  = sqrtf(redp[0] + redp[1] + redp[2] + redp[3]);
    const float invd = 1.0f / (nrm + 1e-8f);
    __syncthreads();                           // bar2: partials consumed

    // ---- encoding: re = clamp(v,-1,1); im = sign(v)*sqrt(1-re^2) ----
    // |q|^2 == 1 exactly => second normalization = 1/4096, folded into epilogue.
    v2f a[16];
#define ENC(k, xval)                                                      \
    {                                                                     \
        const float v   = (xval) * invd;                                  \
        const float re  = fminf(fmaxf(v, -1.0f), 1.0f);                   \
        const float imb = __builtin_amdgcn_sqrtf(fmaxf(1.0f - re * re, 0.f)); \
        const float im  = (v > 0.f) ? imb : ((v < 0.f) ? -imb : 0.f);     \
        v2f q; q.x = re; q.y = im;                                        \
        a[k] = q;                                                         \
    }
#pragma unroll
    for (int j = 0; j < 4; ++j) {
        const float4 xq = xv[j];
        ENC(4 * j + 0, xq.x); ENC(4 * j + 1, xq.y);
        ENC(4 * j + 2, xq.z); ENC(4 * j + 3, xq.w);
    }
#undef ENC

#define CTV(q) ({ v2f _c; _c.x = BCAST(cl, q); _c.y = _c.x; _c; })
#define SNV(q) ({ float _s = BCAST(sl, q); v2f _v; _v.x = _s; _v.y = -_s; _v; })

    const int c1 = (t & 7) ^ ((t >> 3) & 7);   // shared swizzle constant

    // ---- pass 1: qubits 0-2 on regs = e bits 0-3 (e = 16t + r) ----
    apply_layer<1, 2, true>(a, CTV(0), SNV(0));
    apply_layer<2, 4, true>(a, CTV(1), SNV(1));
    apply_layer<4, 8, true>(a, CTV(2), SNV(2));
    {
        // L1 write: addr = (t<<7 | c1<<4) ^ (p<<4); b128 = {a[p], a[p+8]}
        const int base1 = (t << 7) | (c1 << 4);
#pragma unroll
        for (int p = 0; p < 8; ++p) {
            v4f w; w.x = a[p].x;     w.y = a[p].y;
            w.z = a[p + 8].x; w.w = a[p + 8].y;
            *(v4f*)(lds + (base1 ^ (p << 4))) = w;
        }
    }
    __syncthreads();                           // bar3: L1 ready

    // ---- pass 2: qubits 3-5 on regs = e bits 3-6; e = (t&7) + 8r + 128g ----
    {
        const int g = t >> 3;
        const int base2 = (c1 << 4) | (g << 10);
#pragma unroll
        for (int m = 0; m < 8; ++m) {          // L1 read: pairs over e bit3
            const v4f v = *(const v4f*)(lds + (base2 ^ ((m << 7) | (m << 4))));
            v2f q0; q0.x = v.x; q0.y = v.y;
            v2f q1; q1.x = v.z; q1.y = v.w;
            a[2 * m]     = q0;                 // r = 2m
            a[2 * m + 1] = q1;                 // r = 2m+1
        }
        apply_layer<1, 2, true>(a, CTV(3), SNV(3));
        apply_layer<2, 4, true>(a, CTV(4), SNV(4));
        apply_layer<4, 8, true>(a, CTV(5), SNV(5));
        // L2 write: SAME address set (in-place per thread); b128 = {a[p],a[p+8]}
#pragma unroll
        for (int p = 0; p < 8; ++p) {
            v4f w; w.x = a[p].x;     w.y = a[p].y;
            w.z = a[p + 8].x; w.w = a[p + 8].y;
            *(v4f*)(lds + (base2 ^ ((p << 7) | (p << 4)))) = w;
        }
    }
    __syncthreads();                           // bar4: L2 ready

    // ---- pass 3: qubits 6-8 on regs = e bits 6-9; e = (t&63) + 64r + 1024w ----
    {
        const int base3 = (((t & 63) ^ ((t >> 3) & 7)) << 4) + ((t >> 6) << 13);
#pragma unroll
        for (int m = 0; m < 8; ++m) {          // L2 read: pairs over e bit6
            const v4f v = *(const v4f*)(lds + (base3 ^ ((m << 10) | (m << 4))));
            v2f q0; q0.x = v.x; q0.y = v.y;
            v2f q1; q1.x = v.z; q1.y = v.w;
            a[2 * m]     = q0;                 // r = 2m
            a[2 * m + 1] = q1;                 // r = 2m+1
        }
        apply_layer<1, 2, true>(a, CTV(6), SNV(6));
        apply_layer<2, 4, true>(a, CTV(7), SNV(7));
        apply_layer<4, 8, true>(a, CTV(8), SNV(8));
        // L3 write: SAME address set (in-place per thread); b128 = {a[p],a[p+8]}
#pragma unroll
        for (int p = 0; p < 8; ++p) {
            v4f w; w.x = a[p].x;     w.y = a[p].y;
            w.z = a[p + 8].x; w.w = a[p + 8].y;
            *(v4f*)(lds + (base3 ^ ((p << 10) | (p << 4)))) = w;
        }
    }
    __syncthreads();                           // bar5: L3 ready

    // ---- pass 4: qubits 9-11 on regs bits0-2 = e bits 9-11, bit3 = e bit0 ----
    // e = 2t + 512k + b0; L3 read: pairs over e bit9 (k even/odd), b0 in-reg.
    {
        const int c4 = ((t >> 2) & 7) ^ ((t >> 5) & 7);
        const int base40 = (t << 5) ^ (c4 << 4);     // b0 = 0
        const int base41 = base40 ^ 16;              // b0 = 1
#pragma unroll
        for (int j = 0; j < 4; ++j) {
            const v4f v0 = *(const v4f*)(lds + base40 + (j << 13));
            const v4f v1 = *(const v4f*)(lds + base41 + (j << 13));
            v2f q; q.x = v0.x; q.y = v0.y; a[2 * j]         = q;   // k=2j,  b0=0
            q.x = v0.z; q.y = v0.w;        a[2 * j + 1]     = q;   // k=2j+1,b0=0
            q.x = v1.x; q.y = v1.y;        a[2 * j + 8]     = q;   // k=2j,  b0=1
            q.x = v1.z; q.y = v1.w;        a[2 * j + 9]     = q;   // k=2j+1,b0=1
        }
        apply_layer<1, 2, true >(a, CTV(9),  SNV(9));   // c=b9,  t=b10
        apply_layer<2, 4, true >(a, CTV(10), SNV(10));  // c=b10, t=b11
        apply_layer<4, 8, false>(a, CTV(11), SNV(11));  // c=b11, t=b0

        // probs epilogue; scale = 1/4096 (encode norm) * (1/sqrt2)^24 = 2^-24
        // non-temporal: 64 MB write stream, never re-read.
        v2f sc2; sc2.x = 0x1p-24f; sc2.y = 0x1p-24f;
        v2f* outp = (v2f*)(out + sbase);
#pragma unroll
        for (int k = 0; k < 8; ++k) {
            const v2f q0 = a[k] * a[k];             // v_pk_mul_f32
            const v2f q1 = a[k | 8] * a[k | 8];
            v2f res; res.x = q0.x + q0.y;
            res.y = q1.x + q1.y;
            res = res * sc2;                        // v_pk_mul_f32
            __builtin_nontemporal_store(res, outp + t + (k << 8));
        }
    }
#undef CTV
#undef SNV
}

extern "C" void kernel_launch(void* const* d_in, const int* in_sizes, int n_in,
                              void* d_out, int out_size, void* d_ws, size_t ws_size,
                              hipStream_t stream) {
    (void)in_sizes; (void)n_in; (void)out_size; (void)d_ws; (void)ws_size;
    const float* state  = (const float*)d_in[0];   // (8,512,4096) fp32
    const float* params = (const float*)d_in[1];   // (12,) fp32
    float* out = (float*)d_out;                    // (8,512,4096) fp32
    qlayer_kernel<<<dim3(4096), dim3(TPB), 0, stream>>>(state, params, out);
}

// Round 7
// 114.953 us; speedup vs baseline: 1.0574x; 1.0053x over previous
//
#include <hip/hip_runtime.h>

#define NQ  12
#define DIM 4096
#define TPB 256

typedef float v2f __attribute__((ext_vector_type(2)));
typedef float v4f __attribute__((ext_vector_type(4)));

// ---------------------------------------------------------------------------
// Round-2 structure (empirical best: 256 thr x 16 amps, 4 passes, 32768 B LDS
// -> 5 blocks/CU, swizzle slot(e) = e ^ (((e>>5)&7)<<1), measured ~0
// conflicts) with TWO barriers deleted:
//   P1->P2 and P2->P3 exchanges are INTRA-WAVE: in both layouts e bits 10-11
//   come from the wave id, so wave w only touches LDS bytes
//   [8192w, 8192w+8192) in P1w/P2r/P2w/P3r/P3w (verified per-pattern; the
//   swizzle xors byte bits 4-6 only). Wave-internal LDS RAW is ordered by
//   program order + lgkmcnt -> no __syncthreads needed until P4, whose read
//   (k spans e bits 9-11) is cross-wave.  Barriers: 5 -> 3.
// Round-3/4/5 lessons: no x-staging (strided loads already hidden); keep 20
// waves/CU (256-thr blocks); LDS pipe is byte-bound, not instr-bound (all-
// b128 rewrite was neutral-to-negative) -> keep mixed b128/b64 exchanges.
// ---------------------------------------------------------------------------

__device__ __forceinline__ float wave_reduce(float v) {
#pragma unroll
    for (int m = 32; m >= 1; m >>= 1) v += __shfl_xor(v, m, 64);
    return v;
}

// broadcast lane q's value to all lanes (lands in SGPR)
#define BCAST(v, q) __uint_as_float(__builtin_amdgcn_readlane(__float_as_uint(v), (q)))

// One circuit layer: unnormalized H on register-bit MC (1/sqrt2 folded into
// epilogue), then (X*RX if XGATE else RX) on bit MT where MC==1.
// ctv = (c,c), snv = (s,-s); off-diag = -i*s, so (-i*s)*z = snv * z.yx.
template <int MC, int MT, bool XGATE>
__device__ __forceinline__ void apply_layer(v2f* a, v2f ctv, v2f snv) {
#pragma unroll
    for (int i = 0; i < 16; ++i) {
        if (i & MC) continue;
        const int j = i | MC;
        const v2f t0 = a[i], t1 = a[j];
        a[i] = t0 + t1;          // v_pk_add_f32
        a[j] = t0 - t1;
    }
#pragma unroll
    for (int i = 0; i < 16; ++i) {
        if (!(i & MC) || (i & MT)) continue;   // control=1, target=0 slot
        const int j = i | MT;
        const v2f b0 = a[i], b1 = a[j];
        const v2f s0 = snv * b0.yx;            // v_pk_mul_f32
        const v2f s1 = snv * b1.yx;
        if (XGATE) {                           // X*RX = [[s, c],[c, s]]
            a[i] = ctv * b1 + s0;              // v_pk_fma_f32
            a[j] = ctv * b0 + s1;
        } else {                               // RX = [[c, s],[s, c]]
            a[i] = ctv * b0 + s1;
            a[j] = ctv * b1 + s0;
        }
    }
}

__global__ __launch_bounds__(TPB, 5) void qlayer_kernel(
        const float* __restrict__ state, const float* __restrict__ params,
        float* __restrict__ out) {
    __shared__ __align__(16) v2f amp[DIM];     // 32768 B exactly -> 5 blocks/CU
    char* const lds = (char*)amp;

    const int t = threadIdx.x;
    const int lane = t & 63;
    const long long sbase = (long long)blockIdx.x * DIM;

    // per-lane angle (lanes 0..11 hold cos/sin(theta_q/2)); broadcast via readlane
    const float th = params[lane < NQ ? lane : 0] * 0.5f;
    const float cl = cosf(th);
    const float sl = sinf(th);

    // ---- load 16 contiguous floats (64 B/thread) + norm reduction ----
    const float4* gp = (const float4*)(state + sbase + t * 16);
    float4 xv[4];
    float ss = 0.f;
#pragma unroll
    for (int j = 0; j < 4; ++j) {
        const float4 v = gp[j];
        xv[j] = v;
        ss = fmaf(v.x, v.x, ss); ss = fmaf(v.y, v.y, ss);
        ss = fmaf(v.z, v.z, ss); ss = fmaf(v.w, v.w, ss);
    }
    ss = wave_reduce(ss);
    if (lane == 0) ((float*)lds)[t >> 6] = ss;
    __syncthreads();                           // bar1: partials visible
    const float* redp = (const float*)lds;
    const float sst = redp[0] + redp[1] + redp[2] + redp[3];
    // invd = 1/(sqrt(sst)+1e-8) ~= rsq(sst): relative error of dropping the
    // +1e-8 is ~1.6e-10 at nrm~64 -- far below fp32 eps. Saves sqrt + divide.
    const float invd = __builtin_amdgcn_rsqf(sst);
    __syncthreads();                           // bar2: partials consumed

    // ---- encoding: re = clamp(v,-1,1); im = sign(v)*sqrt(1-re^2) ----
    // |q|^2 == 1 exactly => second normalization = 1/4096, folded into epilogue.
    v2f a[16];
#define ENC(k, xval)                                                      \
    {                                                                     \
        const float v   = (xval) * invd;                                  \
        const float re  = fminf(fmaxf(v, -1.0f), 1.0f);                   \
        const float imb = __builtin_amdgcn_sqrtf(fmaxf(1.0f - re * re, 0.f)); \
        const float im  = (v > 0.f) ? imb : ((v < 0.f) ? -imb : 0.f);     \
        v2f q; q.x = re; q.y = im;                                        \
        a[k] = q;                                                         \
    }
#pragma unroll
    for (int j = 0; j < 4; ++j) {
        const float4 xq = xv[j];
        ENC(4 * j + 0, xq.x); ENC(4 * j + 1, xq.y);
        ENC(4 * j + 2, xq.z); ENC(4 * j + 3, xq.w);
    }
#undef ENC

#define CTV(q) ({ v2f _c; _c.x = BCAST(cl, q); _c.y = _c.x; _c; })
#define SNV(q) ({ float _s = BCAST(sl, q); v2f _v; _v.x = _s; _v.y = -_s; _v; })

    // ---- pass 1: layers 0..2 on idx bits {0,1,2,3}; e = 16t + 2k + b0 ----
    apply_layer<1, 2, true>(a, CTV(0), SNV(0));
    apply_layer<2, 4, true>(a, CTV(1), SNV(1));
    apply_layer<4, 8, true>(a, CTV(2), SNV(2));
    {
        // e>>5 = t>>1; xor bits fold as byte = 128t | ((k ^ ((t>>1)&7))<<4)
        const int v1b = (t << 7) | (((t >> 1) & 7) << 4);
#pragma unroll
        for (int k = 0; k < 8; ++k) {
            v4f w; w.x = a[2 * k].x; w.y = a[2 * k].y;
            w.z = a[2 * k + 1].x; w.w = a[2 * k + 1].y;
            *(v4f*)(lds + (v1b ^ (k << 4))) = w;
        }
    }
    // NO barrier: P1 write / P2 read are wave-slab-local ([8192w, 8192w+8192))

    // ---- pass 2: layers 3..5 on idx bits {3,4,5,6}; e = (t&7) + 8r + 128g ----
    {
        // e>>5 = (r>>2) + 4g ; slot bit3 = (r&1)^(g&1), bits1-2 ^= (r>>2)
        const int g  = t >> 3;
        const int gp2 = g & 1;
        const int baseE = ((t & 7) << 3) + (g << 10) + (gp2 << 6);        // r even
        const int baseO = ((t & 7) << 3) + (g << 10) + ((1 - gp2) << 6);  // r odd
#pragma unroll
        for (int r = 0; r < 16; ++r)
            a[r] = *(const v2f*)(lds +
                ((((r & 1) ? baseO : baseE) ^ ((r >> 2) << 4)) + ((r >> 1) << 7)));
        apply_layer<1, 2, true>(a, CTV(3), SNV(3));
        apply_layer<2, 4, true>(a, CTV(4), SNV(4));
        apply_layer<4, 8, true>(a, CTV(5), SNV(5));
#pragma unroll
        for (int r = 0; r < 16; ++r)
            *(v2f*)(lds +
                ((((r & 1) ? baseO : baseE) ^ ((r >> 2) << 4)) + ((r >> 1) << 7))) = a[r];
    }
    // NO barrier: P2 write / P3 read are wave-slab-local

    // ---- pass 3: layers 6..8 on idx bits {6,7,8,9}; e = (t&63) + 64r + 1024w ----
    {
        // e>>5 = ((t>>5)&1) + 2r + 32w ; slot bit1 ^= (t>>5)&1, bits2-3 ^= r&3
        const int b3b = (((t & 63) ^ (((t >> 5) & 1) << 1)) << 3) + ((t >> 6) << 13);
#pragma unroll
        for (int r = 0; r < 16; ++r)
            a[r] = *(const v2f*)(lds + ((b3b ^ ((r & 3) << 5)) + (r << 9)));
        apply_layer<1, 2, true>(a, CTV(6), SNV(6));
        apply_layer<2, 4, true>(a, CTV(7), SNV(7));
        apply_layer<4, 8, true>(a, CTV(8), SNV(8));
#pragma unroll
        for (int r = 0; r < 16; ++r)
            *(v2f*)(lds + ((b3b ^ ((r & 3) << 5)) + (r << 9))) = a[r];
    }
    __syncthreads();   // bar3: REQUIRED -- P4 reads span all waves' slabs

    // ---- pass 4: layers 9..11 on idx bits {9,10,11,0}; e = 2t + 512k + b0 ----
    {
        // e>>5 = (t>>4) + 16k ; xor term depends only on t:
        // byte = (16t ^ (((t>>4)&7)<<4)) + 4096k ; (b0=0,b0=1) adjacent -> b128
        const int F0b = (t << 4) ^ (((t >> 4) & 7) << 4);
#pragma unroll
        for (int k = 0; k < 8; ++k) {
            const v4f v = *(const v4f*)(lds + (F0b + (k << 12)));
            v2f q0; q0.x = v.x; q0.y = v.y;
            v2f q1; q1.x = v.z; q1.y = v.w;
            a[k] = q0;       // bit0 = 0
            a[k + 8] = q1;   // bit0 = 1
        }
        apply_layer<1, 2, true >(a, CTV(9),  SNV(9));   // c=b9,  t=b10
        apply_layer<2, 4, true >(a, CTV(10), SNV(10));  // c=b10, t=b11
        apply_layer<4, 8, false>(a, CTV(11), SNV(11));  // c=b11, t=b0

        // probs epilogue; scale = 1/4096 (encode norm) * (1/sqrt2)^24 = 2^-24
        // non-temporal: 64 MB write stream, never re-read -> don't churn L2.
        v2f sc2; sc2.x = 0x1p-24f; sc2.y = 0x1p-24f;
        v2f* outp = (v2f*)(out + sbase);
#pragma unroll
        for (int k = 0; k < 8; ++k) {
            const v2f q0 = a[k] * a[k];             // v_pk_mul_f32
            const v2f q1 = a[k | 8] * a[k | 8];
            v2f res; res.x = q0.x + q0.y;
            res.y = q1.x + q1.y;
            res = res * sc2;                        // v_pk_mul_f32
            __builtin_nontemporal_store(res, outp + t + (k << 8));
        }
    }
#undef CTV
#undef SNV
}

extern "C" void kernel_launch(void* const* d_in, const int* in_sizes, int n_in,
                              void* d_out, int out_size, void* d_ws, size_t ws_size,
                              hipStream_t stream) {
    (void)in_sizes; (void)n_in; (void)out_size; (void)d_ws; (void)ws_size;
    const float* state  = (const float*)d_in[0];   // (8,512,4096) fp32
    const float* params = (const float*)d_in[1];   // (12,) fp32
    float* out = (float*)d_out;                    // (8,512,4096) fp32
    qlayer_kernel<<<dim3(4096), dim3(TPB), 0, stream>>>(state, params, out);
}